// Round 8
// baseline (817.034 us; speedup 1.0000x reference)
//
#include <hip/hip_runtime.h>
#include <hip/hip_bf16.h>

typedef __attribute__((ext_vector_type(4))) float f32x4;
typedef __attribute__((ext_vector_type(8))) short s16x8;

#define NCLS 16
#define NCAT 4096
#define NOUT 512
#define NBS  4096

#define BM 128
#define BN 128
#define BK 32
#define NSPLIT 8
#define KSPLIT (NCAT / NSPLIT)   // 512
#define NIT    (KSPLIT / BK)     // 16
#define MAXTILES 48

// d_ws int layout
#define WS_NT    0
#define WS_CBASE 1     // [17]
#define WS_TCLS  32    // [MAXTILES]
#define WS_TM0   96    // [MAXTILES]
#define WS_SIDX  160   // [4096]

// ---------------- prep: histogram + parallel scan + tile map + scatter ----------------
__global__ __launch_bounds__(256) void prep_kernel(const int* __restrict__ cls,
                                                   int* __restrict__ ws) {
  __shared__ int lcnt[NCLS * 256];
  __shared__ int cb[NCLS];
  const int t = threadIdx.x;

  int cl[16];
  #pragma unroll
  for (int j = 0; j < 16; ++j) cl[j] = cls[j * 256 + t];

  int cnt[NCLS];
  #pragma unroll
  for (int c = 0; c < NCLS; ++c) cnt[c] = 0;
  #pragma unroll
  for (int j = 0; j < 16; ++j) {
    #pragma unroll
    for (int c = 0; c < NCLS; ++c) cnt[c] += (cl[j] == c) ? 1 : 0;
  }
  #pragma unroll
  for (int c = 0; c < NCLS; ++c) lcnt[c * 256 + t] = cnt[c];
  __syncthreads();

  for (int d = 1; d < 256; d <<= 1) {
    int add[NCLS];
    #pragma unroll
    for (int c = 0; c < NCLS; ++c) add[c] = (t >= d) ? lcnt[c * 256 + t - d] : 0;
    __syncthreads();
    #pragma unroll
    for (int c = 0; c < NCLS; ++c) if (t >= d) lcnt[c * 256 + t] += add[c];
    __syncthreads();
  }

  if (t == 0) {
    int acc = 0, ntt = 0;
    for (int c = 0; c < NCLS; ++c) {
      cb[c] = acc;
      ws[WS_CBASE + c] = acc;
      int tot = lcnt[c * 256 + 255];
      for (int m0 = 0; m0 < tot; m0 += BM) {
        ws[WS_TCLS + ntt] = c;
        ws[WS_TM0 + ntt] = m0;
        ++ntt;
      }
      acc += tot;
    }
    ws[WS_CBASE + NCLS] = acc;
    ws[WS_NT] = ntt;
  }
  __syncthreads();

  #pragma unroll
  for (int j = 0; j < 16; ++j) {
    int c = cl[j];
    int within = 0;
    #pragma unroll
    for (int j2 = 0; j2 < 16; ++j2) within += (j2 < j && cl[j2] == c) ? 1 : 0;
    ws[WS_SIDX + cb[c] + (lcnt[c * 256 + t] - cnt[c]) + within] = j * 256 + t;
  }
}

// ---------------- gemm helpers ----------------
typedef const __attribute__((address_space(1))) void* gas_ptr;
typedef __attribute__((address_space(3))) void* las_ptr;

__device__ __forceinline__ void gl_lds16(const void* g, void* l) {
  __builtin_amdgcn_global_load_lds((gas_ptr)g, (las_ptr)l, 16, 0, 0);
}

// Split pair into hi/lo bf16 (hi = rn(x), lo = rn(x - hi)); packed u32 each.
__device__ __forceinline__ void pk2(float x0, float x1, unsigned& hb, unsigned& lb) {
  __hip_bfloat162 h2 = __float22bfloat162_rn(make_float2(x0, x1));
  float2 hf = __bfloat1622float2(h2);
  __hip_bfloat162 l2 = __float22bfloat162_rn(make_float2(x0 - hf.x, x1 - hf.y));
  __builtin_memcpy(&hb, &h2, 4);
  __builtin_memcpy(&lb, &l2, 4);
}

__device__ __forceinline__ void cvt8(f32x4 p, f32x4 q, s16x8& hi, s16x8& lo) {
  union { s16x8 v; unsigned u[4]; } H, L;
  pk2(p[0], p[1], H.u[0], L.u[0]);
  pk2(p[2], p[3], H.u[1], L.u[1]);
  pk2(q[0], q[1], H.u[2], L.u[2]);
  pk2(q[2], q[3], H.u[3], L.u[3]);
  hi = H.v; lo = L.v;
}

// --- grouped GEMM: 32KB single-buffer LDS -> 5 blocks/CU, DMA stage, consume-convert ---
__global__ __launch_bounds__(256, 5) void gemm_kernel(const float* __restrict__ batch,
                                                      const float* __restrict__ W,
                                                      const int* __restrict__ ws,
                                                      float* __restrict__ out) {
  const int tile = blockIdx.x;
  if (tile >= ws[WS_NT]) return;
  const int c    = ws[WS_TCLS + tile];
  const int m0   = ws[WS_TM0 + tile];
  const int base = ws[WS_CBASE + c];
  const int Mc   = ws[WS_CBASE + c + 1] - base;
  const int n0   = blockIdx.y * BN;
  const int k0   = blockIdx.z * KSPLIT;
  const int* sidx = ws + WS_SIDX + base;

  // LDS: single buffer [ A 128x32 fp32 (16KB) | B 128x32 fp32 (16KB) ] = 32 KB
  __shared__ char lds[32768];
  char* const ldsA = lds;
  char* const ldsB = lds + 16384;

  const int t    = threadIdx.x;
  const int lane = t & 63;
  const int wv   = t >> 6;
  const int l15  = lane & 15;

  // --- DMA source addresses, pre-swizzled (linear LDS dest == swizzled layout) ---
  // gl_lds16: 1024B = 8 rows x 128B. lane l: row +(l>>3), chunk ((l&7)^(l>>3))*16.
  const int rsub = lane >> 3;
  const int cswz = (((lane & 7) ^ rsub) << 4);
  const char* aga[4];
  const char* bga[4];
  #pragma unroll
  for (int j = 0; j < 4; ++j) {
    const int rr = 32 * wv + 8 * j + rsub;
    const int ar = sidx[min(m0 + rr, Mc - 1)];
    aga[j] = (const char*)batch + ((size_t)ar * NCAT + k0) * 4 + cswz;
    const int br = c * NOUT + n0 + rr;
    bga[j] = (const char*)W + ((size_t)br * NCAT + k0) * 4 + cswz;
  }

  const int wm  = (wv >> 1) * 64;
  const int wn  = (wv & 1) * 64;
  const int kb0 = (lane >> 4) * 32;  // lane's 8-float k-group byte base within 128B row

  f32x4 acc[4][4];
  #pragma unroll
  for (int i = 0; i < 4; ++i)
    #pragma unroll
    for (int j = 0; j < 4; ++j) acc[i][j] = (f32x4){0.f, 0.f, 0.f, 0.f};

  for (int it = 0; it < NIT; ++it) {
    // all waves done reading the buffer from the previous iteration
    __builtin_amdgcn_s_barrier();
    asm volatile("" ::: "memory");

    // stage tile it (8 DMA instrs per wave; 32 KB per block)
    const int kbyte = it * 128;
    #pragma unroll
    for (int j = 0; j < 4; ++j)
      gl_lds16(aga[j] + kbyte, ldsA + (32 * wv + 8 * j) * 128);
    #pragma unroll
    for (int j = 0; j < 4; ++j)
      gl_lds16(bga[j] + kbyte, ldsB + (32 * wv + 8 * j) * 128);

    asm volatile("s_waitcnt vmcnt(0)" ::: "memory");
    __builtin_amdgcn_s_barrier();
    asm volatile("" ::: "memory");

    // consume: ds_read fp32 -> convert hi/lo bf16 -> 3x MFMA
    s16x8 Ah[4], Al[4], Bh[4], Bl[4];
    #pragma unroll
    for (int i = 0; i < 4; ++i) {
      const int m = wm + i * 16 + l15;
      const char* rowp = ldsA + m * 128;
      const int swzm = (m & 7) << 4;
      f32x4 p = *(const f32x4*)(rowp + (kb0 ^ swzm));
      f32x4 q = *(const f32x4*)(rowp + ((kb0 + 16) ^ swzm));
      cvt8(p, q, Ah[i], Al[i]);
      const int n = wn + i * 16 + l15;
      const char* rowq = ldsB + n * 128;
      const int swzn = (n & 7) << 4;
      f32x4 rr = *(const f32x4*)(rowq + (kb0 ^ swzn));
      f32x4 ss = *(const f32x4*)(rowq + ((kb0 + 16) ^ swzn));
      cvt8(rr, ss, Bh[i], Bl[i]);
    }
    __builtin_amdgcn_s_setprio(1);
    #pragma unroll
    for (int i = 0; i < 4; ++i)
      #pragma unroll
      for (int j = 0; j < 4; ++j) {
        acc[i][j] = __builtin_amdgcn_mfma_f32_16x16x32_bf16(Ah[i], Bh[j], acc[i][j], 0, 0, 0);
        acc[i][j] = __builtin_amdgcn_mfma_f32_16x16x32_bf16(Ah[i], Bl[j], acc[i][j], 0, 0, 0);
        acc[i][j] = __builtin_amdgcn_mfma_f32_16x16x32_bf16(Al[i], Bh[j], acc[i][j], 0, 0, 0);
      }
    __builtin_amdgcn_s_setprio(0);
  }

  // ---- epilogue: C/D layout col=lane&15, row=(lane>>4)*4+reg ----
  const int r4 = (lane >> 4) * 4;
  #pragma unroll
  for (int i = 0; i < 4; ++i) {
    #pragma unroll
    for (int jj = 0; jj < 4; ++jj) {
      const int mloc = wm + i * 16 + r4 + jj;
      const int gm = m0 + mloc;
      if (gm < Mc) {
        const int sample = sidx[gm];
        float* orow = out + (size_t)sample * NOUT + n0 + wn;
        #pragma unroll
        for (int j = 0; j < 4; ++j) {
          atomicAdd(orow + j * 16 + l15, acc[i][j][jj]);
        }
      }
    }
  }
}

extern "C" void kernel_launch(void* const* d_in, const int* in_sizes, int n_in,
                              void* d_out, int out_size, void* d_ws, size_t ws_size,
                              hipStream_t stream) {
  const float* batch = (const float*)d_in[0];
  const int*   cls   = (const int*)d_in[1];
  const float* W     = (const float*)d_in[2];
  float* out = (float*)d_out;
  int*   ws  = (int*)d_ws;

  prep_kernel<<<1, 256, 0, stream>>>(cls, ws);
  hipMemsetAsync(d_out, 0, (size_t)out_size * sizeof(float), stream);
  gemm_kernel<<<dim3(MAXTILES, NOUT / BN, NSPLIT), 256, 0, stream>>>(batch, W, ws, out);
}

// Round 9
// 329.338 us; speedup vs baseline: 2.4808x; 2.4808x over previous
//
#include <hip/hip_runtime.h>
#include <hip/hip_bf16.h>

typedef __attribute__((ext_vector_type(4))) float f32x4;
typedef __attribute__((ext_vector_type(8))) short s16x8;

#define NCLS 16
#define NCAT 4096
#define NOUT 512
#define NBS  4096

#define BM 64
#define BN 64
#define BK 64                    // fp32 k per LDS tile; row = 256 B
#define NSPLIT 2
#define KSPLIT (NCAT / NSPLIT)   // 2048
#define NIT    (KSPLIT / BK)     // 32
#define MAXTILES 96

// d_ws int layout
#define WS_NT    0
#define WS_CBASE 1     // [17]
#define WS_TCLS  32    // [MAXTILES]
#define WS_TM0   128   // [MAXTILES]
#define WS_SIDX  224   // [4096]

// ---------------- prep: histogram + parallel scan + tile map + scatter ----------------
__global__ __launch_bounds__(256) void prep_kernel(const int* __restrict__ cls,
                                                   int* __restrict__ ws) {
  __shared__ int lcnt[NCLS * 256];
  __shared__ int cb[NCLS];
  const int t = threadIdx.x;

  int cl[16];
  #pragma unroll
  for (int j = 0; j < 16; ++j) cl[j] = cls[j * 256 + t];

  int cnt[NCLS];
  #pragma unroll
  for (int c = 0; c < NCLS; ++c) cnt[c] = 0;
  #pragma unroll
  for (int j = 0; j < 16; ++j) {
    #pragma unroll
    for (int c = 0; c < NCLS; ++c) cnt[c] += (cl[j] == c) ? 1 : 0;
  }
  #pragma unroll
  for (int c = 0; c < NCLS; ++c) lcnt[c * 256 + t] = cnt[c];
  __syncthreads();

  for (int d = 1; d < 256; d <<= 1) {
    int add[NCLS];
    #pragma unroll
    for (int c = 0; c < NCLS; ++c) add[c] = (t >= d) ? lcnt[c * 256 + t - d] : 0;
    __syncthreads();
    #pragma unroll
    for (int c = 0; c < NCLS; ++c) if (t >= d) lcnt[c * 256 + t] += add[c];
    __syncthreads();
  }

  if (t == 0) {
    int acc = 0, ntt = 0;
    for (int c = 0; c < NCLS; ++c) {
      cb[c] = acc;
      ws[WS_CBASE + c] = acc;
      int tot = lcnt[c * 256 + 255];
      for (int m0 = 0; m0 < tot; m0 += BM) {
        ws[WS_TCLS + ntt] = c;
        ws[WS_TM0 + ntt] = m0;
        ++ntt;
      }
      acc += tot;
    }
    ws[WS_CBASE + NCLS] = acc;
    ws[WS_NT] = ntt;
  }
  __syncthreads();

  #pragma unroll
  for (int j = 0; j < 16; ++j) {
    int c = cl[j];
    int within = 0;
    #pragma unroll
    for (int j2 = 0; j2 < 16; ++j2) within += (j2 < j && cl[j2] == c) ? 1 : 0;
    ws[WS_SIDX + cb[c] + (lcnt[c * 256 + t] - cnt[c]) + within] = j * 256 + t;
  }
}

// ---------------- gemm helpers ----------------
typedef const __attribute__((address_space(1))) void* gas_ptr;
typedef __attribute__((address_space(3))) void* las_ptr;

__device__ __forceinline__ void gl_lds16(const void* g, void* l) {
  __builtin_amdgcn_global_load_lds((gas_ptr)g, (las_ptr)l, 16, 0, 0);
}

// Split pair into hi/lo bf16 (hi = rn(x), lo = rn(x - hi)); packed u32 each.
__device__ __forceinline__ void pk2(float x0, float x1, unsigned& hb, unsigned& lb) {
  __hip_bfloat162 h2 = __float22bfloat162_rn(make_float2(x0, x1));
  float2 hf = __bfloat1622float2(h2);
  __hip_bfloat162 l2 = __float22bfloat162_rn(make_float2(x0 - hf.x, x1 - hf.y));
  __builtin_memcpy(&hb, &h2, 4);
  __builtin_memcpy(&lb, &l2, 4);
}

__device__ __forceinline__ void cvt8(f32x4 p, f32x4 q, s16x8& hi, s16x8& lo) {
  union { s16x8 v; unsigned u[4]; } H, L;
  pk2(p[0], p[1], H.u[0], L.u[0]);
  pk2(p[2], p[3], H.u[1], L.u[1]);
  pk2(q[0], q[1], H.u[2], L.u[2]);
  pk2(q[2], q[3], H.u[3], L.u[3]);
  hi = H.v; lo = L.v;
}

// --- grouped GEMM: 64x64 tile, 32KB LDS, 4 blocks/CU, DMA stage, consume-convert ---
__global__ __launch_bounds__(256, 4) void gemm_kernel(const float* __restrict__ batch,
                                                      const float* __restrict__ W,
                                                      const int* __restrict__ ws,
                                                      float* __restrict__ out) {
  const int tile = blockIdx.x;
  if (tile >= ws[WS_NT]) return;
  const int c    = ws[WS_TCLS + tile];
  const int m0   = ws[WS_TM0 + tile];
  const int base = ws[WS_CBASE + c];
  const int Mc   = ws[WS_CBASE + c + 1] - base;
  const int n0   = blockIdx.y * BN;
  const int k0   = blockIdx.z * KSPLIT;
  const int* sidx = ws + WS_SIDX + base;

  // LDS: single buffer [ A 64x64 fp32 (16KB) | B 64x64 fp32 (16KB) ] = 32 KB
  __shared__ char lds[32768];
  char* const ldsA = lds;
  char* const ldsB = lds + 16384;

  const int t    = threadIdx.x;
  const int lane = t & 63;
  const int wv   = t >> 6;
  const int l15  = lane & 15;

  // --- DMA source addresses, pre-swizzled (linear LDS dest == swizzled layout) ---
  // gl_lds16 writes 1024B = 4 rows x 256B. lane l: row +(l>>4), 16B chunk (l&15).
  // Want LDS[r][ch] = G[r][ch ^ (r&15)]  ->  source chunk = (l&15) ^ (r&15).
  const int rsub = lane >> 4;           // row within instr (0..3)
  const char* aga[4];
  const char* bga[4];
  #pragma unroll
  for (int j = 0; j < 4; ++j) {
    const int rr = 16 * wv + 4 * j + rsub;              // tile row 0..63
    const int srcb = ((lane & 15) ^ (rr & 15)) << 4;    // swizzled 16B chunk
    const int ar = sidx[min(m0 + rr, Mc - 1)];
    aga[j] = (const char*)batch + ((size_t)ar * NCAT + k0) * 4 + srcb;
    const int br = c * NOUT + n0 + rr;
    bga[j] = (const char*)W + ((size_t)br * NCAT + k0) * 4 + srcb;
  }

  const int wm  = (wv >> 1) * 32;   // wave output block: 32 rows x 32 cols
  const int wn  = (wv & 1) * 32;
  const int kg  = (lane >> 4) * 32; // lane's 8-float k-group byte base (within 32-k step)

  f32x4 acc[2][2];
  #pragma unroll
  for (int i = 0; i < 2; ++i)
    #pragma unroll
    for (int j = 0; j < 2; ++j) acc[i][j] = (f32x4){0.f, 0.f, 0.f, 0.f};

  for (int it = 0; it < NIT; ++it) {
    // all waves done reading the buffer from the previous iteration
    __builtin_amdgcn_s_barrier();
    asm volatile("" ::: "memory");

    // stage tile it (8 DMA instrs per wave; 32 KB per block)
    const int kbyte = it * 256;
    #pragma unroll
    for (int j = 0; j < 4; ++j)
      gl_lds16(aga[j] + kbyte, ldsA + (16 * wv + 4 * j) * 256);
    #pragma unroll
    for (int j = 0; j < 4; ++j)
      gl_lds16(bga[j] + kbyte, ldsB + (16 * wv + 4 * j) * 256);

    asm volatile("s_waitcnt vmcnt(0)" ::: "memory");
    __builtin_amdgcn_s_barrier();
    asm volatile("" ::: "memory");

    // consume: ds_read fp32 (swizzled) -> convert hi/lo bf16 -> 3x MFMA, 2 k-steps
    #pragma unroll
    for (int ks = 0; ks < 2; ++ks) {
      s16x8 Ah[2], Al[2], Bh[2], Bl[2];
      #pragma unroll
      for (int i = 0; i < 2; ++i) {
        const int m = wm + i * 16 + l15;
        const char* rowp = ldsA + m * 256;
        const int sw = (m & 15) << 4;
        f32x4 p = *(const f32x4*)(rowp + ((ks * 128 + kg) ^ sw));
        f32x4 q = *(const f32x4*)(rowp + ((ks * 128 + kg + 16) ^ sw));
        cvt8(p, q, Ah[i], Al[i]);
        const int n = wn + i * 16 + l15;
        const char* rowq = ldsB + n * 256;
        const int swn = (n & 15) << 4;
        f32x4 rr = *(const f32x4*)(rowq + ((ks * 128 + kg) ^ swn));
        f32x4 ss = *(const f32x4*)(rowq + ((ks * 128 + kg + 16) ^ swn));
        cvt8(rr, ss, Bh[i], Bl[i]);
      }
      __builtin_amdgcn_s_setprio(1);
      #pragma unroll
      for (int i = 0; i < 2; ++i)
        #pragma unroll
        for (int j = 0; j < 2; ++j) {
          acc[i][j] = __builtin_amdgcn_mfma_f32_16x16x32_bf16(Ah[i], Bh[j], acc[i][j], 0, 0, 0);
          acc[i][j] = __builtin_amdgcn_mfma_f32_16x16x32_bf16(Ah[i], Bl[j], acc[i][j], 0, 0, 0);
          acc[i][j] = __builtin_amdgcn_mfma_f32_16x16x32_bf16(Al[i], Bh[j], acc[i][j], 0, 0, 0);
        }
      __builtin_amdgcn_s_setprio(0);
    }
  }

  // ---- epilogue: C/D layout col=lane&15, row=(lane>>4)*4+reg ----
  const int r4 = (lane >> 4) * 4;
  #pragma unroll
  for (int i = 0; i < 2; ++i) {
    #pragma unroll
    for (int jj = 0; jj < 4; ++jj) {
      const int mloc = wm + i * 16 + r4 + jj;
      const int gm = m0 + mloc;
      if (gm < Mc) {
        const int sample = sidx[gm];
        float* orow = out + (size_t)sample * NOUT + n0 + wn;
        #pragma unroll
        for (int j = 0; j < 2; ++j) {
          atomicAdd(orow + j * 16 + l15, acc[i][j][jj]);
        }
      }
    }
  }
}

extern "C" void kernel_launch(void* const* d_in, const int* in_sizes, int n_in,
                              void* d_out, int out_size, void* d_ws, size_t ws_size,
                              hipStream_t stream) {
  const float* batch = (const float*)d_in[0];
  const int*   cls   = (const int*)d_in[1];
  const float* W     = (const float*)d_in[2];
  float* out = (float*)d_out;
  int*   ws  = (int*)d_ws;

  prep_kernel<<<1, 256, 0, stream>>>(cls, ws);
  hipMemsetAsync(d_out, 0, (size_t)out_size * sizeof(float), stream);
  gemm_kernel<<<dim3(MAXTILES, NOUT / BN, NSPLIT), 256, 0, stream>>>(batch, W, ws, out);
}